// Round 2
// baseline (4251.322 us; speedup 1.0000x reference)
//
#include <hip/hip_runtime.h>
#include <hip/hip_bf16.h>

#define N_NODES 100000
#define N_EDGES 3200000
#define F_IN    100
#define H_DIM   64
#define C_NUM   18

// ---- dtype-flexible loads (flags decided at runtime by detect_kernel) ----
__device__ __forceinline__ float ldf(const void* p, long long i, int isbf) {
    if (isbf) return __bfloat162float(((const __hip_bfloat16*)p)[i]);
    return ((const float*)p)[i];
}
__device__ __forceinline__ int ldi(const void* p, long long i, int is64) {
    if (is64) return (int)(((const long long*)p)[i]);
    return ((const int*)p)[i];
}

// ---- probe input dtypes; write flags; stamp diagnostic marker into d_out ----
__global__ void detect_kernel(const void* ei, const void* x, int* flags, void* dout)
{
    if (threadIdx.x != 0 || blockIdx.x != 0) return;
    // edge_index: int64 iff first 128 int64-interpreted values are valid node ids
    const long long* e64 = (const long long*)ei;
    int ok64 = 1;
    for (int i = 0; i < 128; ++i) {
        long long v = e64[i];
        if (v < 0 || v >= N_NODES) { ok64 = 0; break; }
    }
    // floats: bf16 iff bf16-interpreted samples of x look like ~N(0,1)
    const __hip_bfloat16* xb = (const __hip_bfloat16*)x;
    int cnt = 0;
    for (int i = 0; i < 256; ++i) {
        float v = fabsf(__bfloat162float(xb[i]));
        if (v == 0.0f || (v > 9.5367431640625e-7f && v < 1.0e6f)) ++cnt;
    }
    int isbf = (cnt >= 240) ? 1 : 0;
    flags[0] = ok64;
    flags[1] = isbf;
    // diagnostic marker: only survives if downstream kernels fail to run
    for (int i = 0; i < C_NUM; ++i) {
        if (isbf) ((__hip_bfloat16*)dout)[i] = __float2bfloat16(0.5f);
        else      ((float*)dout)[i] = 0.5f;
    }
}

// ---- zero agg (and deg on first call) ----
__global__ void GraphSAGE_17824114278988_kernel(float* __restrict__ agg,
                                                int* __restrict__ deg, int zero_deg)
{
    long long i = (long long)blockIdx.x * blockDim.x + threadIdx.x;
    if (i < (long long)N_NODES * H_DIM) agg[i] = 0.0f;
    if (zero_deg && i < N_NODES) deg[(int)i] = 0;
}

// ---- in-degree count ----
__global__ void deg_kernel(const void* ei, int* __restrict__ deg, const int* __restrict__ flags)
{
    long long e = (long long)blockIdx.x * blockDim.x + threadIdx.x;
    if (e >= N_EDGES) return;
    int d = ldi(ei, (long long)N_EDGES + e, flags[0]);
    atomicAdd(&deg[d], 1);
}

// ---- embedding: h = relu(x @ W + b), one 64-thread block per node ----
__global__ void embed_kernel(const void* x, const void* W, const void* b,
                             float* __restrict__ h, const int* __restrict__ flags)
{
    __shared__ float xs[F_IN];
    const int n = blockIdx.x;
    const int t = threadIdx.x;        // 0..63, lane = out feature
    const int isbf = flags[1];
    for (int i = t; i < F_IN; i += 64) xs[i] = ldf(x, (long long)n * F_IN + i, isbf);
    __syncthreads();
    float acc = ldf(b, t, isbf);
#pragma unroll 4
    for (int k = 0; k < F_IN; ++k)
        acc = fmaf(xs[k], ldf(W, (long long)k * H_DIM + t, isbf), acc);
    h[(size_t)n * H_DIM + t] = fmaxf(acc, 0.0f);
}

// ---- edge scatter: agg[dst] += w * h[src], one wave per edge, lane = feature ----
__global__ void scatter_kernel(const float* __restrict__ h, const void* ei, const void* ew,
                               float* __restrict__ agg, const int* __restrict__ flags,
                               int use_w)
{
    const int l = threadIdx.x & 63;
    const long long e = ((long long)blockIdx.x * blockDim.x + threadIdx.x) >> 6;
    if (e >= N_EDGES) return;
    const int is64 = flags[0];
    int s = ldi(ei, e, is64);
    int d = ldi(ei, (long long)N_EDGES + e, is64);
    float w = 1.0f;
    if (use_w) w = ldf(ew, e, flags[1]);
    atomicAdd(&agg[(size_t)d * H_DIM + l], w * h[(size_t)s * H_DIM + l]);
}

// ---- node transform: out = norm(mean @ Wl + bl + h @ Wr), wave per node ----
template <int COUT, bool RELU, bool FINAL>
__global__ void transform_kernel(float* __restrict__ h,
                                 const float* __restrict__ agg,
                                 const int* __restrict__ deg,
                                 const void* Wl, const void* bl, const void* Wr,
                                 const int* __restrict__ flags, void* dout)
{
    __shared__ float Wl_s[H_DIM * COUT];
    __shared__ float Wr_s[H_DIM * COUT];
    const int t = threadIdx.x;         // 256 threads = 4 waves
    const int isbf = flags[1];
    for (int i = t; i < H_DIM * COUT; i += 256) {
        Wl_s[i] = ldf(Wl, i, isbf);
        Wr_s[i] = ldf(Wr, i, isbf);
    }
    __syncthreads();

    const int wave = t >> 6;
    const int l    = t & 63;
    const int li   = (l < COUT) ? l : 0;
    const float bias = (l < COUT) ? ldf(bl, li, isbf) : 0.0f;
    const int stride = gridDim.x * 4;

    for (int n = blockIdx.x * 4 + wave; n < N_NODES; n += stride) {
        float hn   = h[(size_t)n * H_DIM + l];
        float inv  = 1.0f / (float)max(deg[n], 1);
        float mean = agg[(size_t)n * H_DIM + l] * inv;

        float o = bias;
#pragma unroll 8
        for (int k = 0; k < H_DIM; ++k) {
            float mk = __shfl(mean, k);
            float hk = __shfl(hn, k);
            o = fmaf(mk, Wl_s[k * COUT + li], o);
            o = fmaf(hk, Wr_s[k * COUT + li], o);
        }
        if (l >= COUT) o = 0.0f;

        float nrm2 = o * o;
#pragma unroll
        for (int off = 32; off >= 1; off >>= 1) nrm2 += __shfl_xor(nrm2, off);
        float val = o / fmaxf(sqrtf(nrm2), 1e-12f);
        if (RELU) val = fmaxf(val, 0.0f);

        if (l < COUT) {
            if (FINAL) {
                if (isbf) ((__hip_bfloat16*)dout)[(size_t)n * COUT + l] = __float2bfloat16(val);
                else      ((float*)dout)[(size_t)n * COUT + l] = val;
            } else {
                h[(size_t)n * H_DIM + l] = val;   // in-place: own row only
            }
        }
    }
}

extern "C" void kernel_launch(void* const* d_in, const int* in_sizes, int n_in,
                              void* d_out, int out_size, void* d_ws, size_t ws_size,
                              hipStream_t stream)
{
    const void* x    = d_in[0];
    const void* ei   = d_in[1];
    const void* ew   = d_in[2];
    const void* embW = d_in[3];
    const void* embB = d_in[4];
    const void* Wl1  = d_in[5];
    const void* bl1  = d_in[6];
    const void* Wr1  = d_in[7];
    const void* Wl2  = d_in[8];
    const void* bl2  = d_in[9];
    const void* Wr2  = d_in[10];
    const void* Wl3  = d_in[11];
    const void* bl3  = d_in[12];
    const void* Wr3  = d_in[13];
    const void* Wl4  = d_in[14];
    const void* bl4  = d_in[15];
    const void* Wr4  = d_in[16];
    (void)in_sizes; (void)n_in; (void)out_size; (void)ws_size;

    char* ws = (char*)d_ws;
    size_t off = 0;
    auto alloc = [&](size_t bytes) -> void* {
        void* p = ws + off;
        off += (bytes + 255) & ~(size_t)255;
        return p;
    };
    float* h     = (float*)alloc((size_t)N_NODES * H_DIM * sizeof(float));  // 25.6 MB
    float* agg   = (float*)alloc((size_t)N_NODES * H_DIM * sizeof(float));  // 25.6 MB
    int*   deg   = (int*)  alloc((size_t)N_NODES * sizeof(int));            // 0.4 MB
    int*   flags = (int*)  alloc(256);

    const int ZB = ( (N_NODES * H_DIM) + 255 ) / 256;   // 25000
    const int EB = ( N_EDGES + 255 ) / 256;             // 12500
    const int SB = ( N_EDGES * 64 + 255 ) / 256;        // 800000 (wave per edge)

    detect_kernel<<<1, 64, 0, stream>>>(ei, x, flags, d_out);
    GraphSAGE_17824114278988_kernel<<<ZB, 256, 0, stream>>>(agg, deg, 1);
    deg_kernel<<<EB, 256, 0, stream>>>(ei, deg, flags);
    embed_kernel<<<N_NODES, 64, 0, stream>>>(x, embW, embB, h, flags);

    // layer 1
    scatter_kernel<<<SB, 256, 0, stream>>>(h, ei, ew, agg, flags, 1);
    transform_kernel<H_DIM, true, false><<<4096, 256, 0, stream>>>(
        h, agg, deg, Wl1, bl1, Wr1, flags, d_out);
    // layer 2
    GraphSAGE_17824114278988_kernel<<<ZB, 256, 0, stream>>>(agg, deg, 0);
    scatter_kernel<<<SB, 256, 0, stream>>>(h, ei, ew, agg, flags, 1);
    transform_kernel<H_DIM, true, false><<<4096, 256, 0, stream>>>(
        h, agg, deg, Wl2, bl2, Wr2, flags, d_out);
    // layer 3
    GraphSAGE_17824114278988_kernel<<<ZB, 256, 0, stream>>>(agg, deg, 0);
    scatter_kernel<<<SB, 256, 0, stream>>>(h, ei, ew, agg, flags, 1);
    transform_kernel<H_DIM, true, false><<<4096, 256, 0, stream>>>(
        h, agg, deg, Wl3, bl3, Wr3, flags, d_out);
    // layer 4 (unweighted, no relu, -> d_out)
    GraphSAGE_17824114278988_kernel<<<ZB, 256, 0, stream>>>(agg, deg, 0);
    scatter_kernel<<<SB, 256, 0, stream>>>(h, ei, ew, agg, flags, 0);
    transform_kernel<C_NUM, false, true><<<4096, 256, 0, stream>>>(
        h, agg, deg, Wl4, bl4, Wr4, flags, d_out);
}

// Round 3
// 2095.250 us; speedup vs baseline: 2.0290x; 2.0290x over previous
//
#include <hip/hip_runtime.h>
#include <hip/hip_bf16.h>

#define N_NODES 100000
#define N_EDGES 3200000
#define F_IN    100
#define H_DIM   64
#define C_NUM   18

// ---- dtype-flexible loads (flags decided at runtime by detect_kernel) ----
__device__ __forceinline__ float ldf(const void* p, long long i, int isbf) {
    if (isbf) return __bfloat162float(((const __hip_bfloat16*)p)[i]);
    return ((const float*)p)[i];
}
__device__ __forceinline__ int ldi(const void* p, long long i, int is64) {
    if (is64) return (int)(((const long long*)p)[i]);
    return ((const int*)p)[i];
}
__device__ __forceinline__ float b2f(__hip_bfloat16 v) { return __bfloat162float(v); }

// ---- probe input dtypes; write flags ----
__global__ void detect_kernel(const void* ei, const void* x, int* flags)
{
    if (threadIdx.x != 0 || blockIdx.x != 0) return;
    const long long* e64 = (const long long*)ei;
    int ok64 = 1;
    for (int i = 0; i < 128; ++i) {
        long long v = e64[i];
        if (v < 0 || v >= N_NODES) { ok64 = 0; break; }
    }
    const __hip_bfloat16* xb = (const __hip_bfloat16*)x;
    int cnt = 0;
    for (int i = 0; i < 256; ++i) {
        float v = fabsf(__bfloat162float(xb[i]));
        if (v == 0.0f || (v > 9.5367431640625e-7f && v < 1.0e6f)) ++cnt;
    }
    flags[0] = ok64;
    flags[1] = (cnt >= 240) ? 1 : 0;
}

// ---- zero deg + global cursor ----
__global__ void init_kernel(int* __restrict__ deg, int* __restrict__ total)
{
    int i = blockIdx.x * blockDim.x + threadIdx.x;
    if (i < N_NODES) deg[i] = 0;
    if (i == 0) *total = 0;
}

// ---- in-degree count ----
__global__ void deg_kernel(const void* ei, int* __restrict__ deg, const int* __restrict__ flags)
{
    long long e = (long long)blockIdx.x * blockDim.x + threadIdx.x;
    if (e >= N_EDGES) return;
    int d = ldi(ei, (long long)N_EDGES + e, flags[0]);
    atomicAdd(&deg[d], 1);
}

// ---- assign CSR segments: wave prefix sum + one atomic per wave ----
__global__ void rowstart_kernel(const int* __restrict__ deg,
                                int* __restrict__ row_start,
                                int* __restrict__ cursor,
                                float* __restrict__ inv_deg,
                                int* __restrict__ total)
{
    const int i = blockIdx.x * blockDim.x + threadIdx.x;
    const int l = threadIdx.x & 63;
    const int d = (i < N_NODES) ? deg[i] : 0;
    int incl = d;
#pragma unroll
    for (int off = 1; off < 64; off <<= 1) {
        int v = __shfl_up(incl, off);
        if (l >= off) incl += v;
    }
    const int wave_total = __shfl(incl, 63);
    int base = 0;
    if (l == 63) base = atomicAdd(total, wave_total);
    base = __shfl(base, 63);
    if (i < N_NODES) {
        int rs = base + incl - d;
        row_start[i] = rs;
        cursor[i]    = rs;
        inv_deg[i]   = 1.0f / (float)max(d, 1);
    }
}

// ---- CSR fill ----
__global__ void fill_kernel(const void* ei, const void* ew,
                            int* __restrict__ cursor,
                            int* __restrict__ csr_src, float* __restrict__ csr_w,
                            const int* __restrict__ flags)
{
    long long e = (long long)blockIdx.x * blockDim.x + threadIdx.x;
    if (e >= N_EDGES) return;
    const int is64 = flags[0];
    int s = ldi(ei, e, is64);
    int d = ldi(ei, (long long)N_EDGES + e, is64);
    int pos = atomicAdd(&cursor[d], 1);
    csr_src[pos] = s;
    csr_w[pos]   = ldf(ew, e, flags[1]);
}

// ---- embedding: h = relu(x @ W + b) -> bf16, one 64-thread block per node ----
__global__ void embed_kernel(const void* x, const void* W, const void* b,
                             __hip_bfloat16* __restrict__ h, const int* __restrict__ flags)
{
    __shared__ float xs[F_IN];
    const int n = blockIdx.x;
    const int t = threadIdx.x;        // 0..63, lane = out feature
    const int isbf = flags[1];
    for (int i = t; i < F_IN; i += 64) xs[i] = ldf(x, (long long)n * F_IN + i, isbf);
    __syncthreads();
    float acc = ldf(b, t, isbf);
#pragma unroll 4
    for (int k = 0; k < F_IN; ++k)
        acc = fmaf(xs[k], ldf(W, (long long)k * H_DIM + t, isbf), acc);
    h[(size_t)n * H_DIM + t] = __float2bfloat16(fmaxf(acc, 0.0f));
}

// ---- fused SAGE layer: CSR gather + mean + two GEMVs + L2norm, wave per node ----
template <int COUT, bool RELU, bool USE_W, bool FINAL>
__global__ void sage_fused(const __hip_bfloat16* __restrict__ h_in,
                           __hip_bfloat16* __restrict__ h_out,
                           const int* __restrict__ csr_src,
                           const float* __restrict__ csr_w,
                           const int* __restrict__ row_start,
                           const int* __restrict__ deg,
                           const float* __restrict__ inv_deg,
                           const void* Wl, const void* bl, const void* Wr,
                           const int* __restrict__ flags, void* dout)
{
    __shared__ float Wl_s[H_DIM * COUT];
    __shared__ float Wr_s[H_DIM * COUT];
    const int t = threadIdx.x;         // 256 threads = 4 waves
    const int isbf = flags[1];
    for (int i = t; i < H_DIM * COUT; i += 256) {
        Wl_s[i] = ldf(Wl, i, isbf);
        Wr_s[i] = ldf(Wr, i, isbf);
    }
    __syncthreads();

    const int wave = t >> 6;
    const int l    = t & 63;
    const int li   = (l < COUT) ? l : 0;
    const float bias = (l < COUT) ? ldf(bl, li, isbf) : 0.0f;
    const int stride = gridDim.x * 4;

    for (int n = blockIdx.x * 4 + wave; n < N_NODES; n += stride) {
        float hn = b2f(h_in[(size_t)n * H_DIM + l]);
        const int start = row_start[n];
        const int d     = deg[n];

        // weighted neighbor sum: lanes fetch up to 64 (src,w) pairs, broadcast via shfl
        float acc = 0.0f;
        for (int j0 = 0; j0 < d; j0 += 64) {
            int m = min(64, d - j0);
            int   sl  = 0;
            float wl_ = 0.0f;
            if (l < m) {
                sl = csr_src[start + j0 + l];
                if (USE_W) wl_ = csr_w[start + j0 + l];
            }
#pragma unroll 4
            for (int jj = 0; jj < m; ++jj) {
                int s = __shfl(sl, jj);
                float w = USE_W ? __shfl(wl_, jj) : 1.0f;
                acc = fmaf(w, b2f(h_in[(size_t)s * H_DIM + l]), acc);
            }
        }
        float mean = acc * inv_deg[n];

        // out[f] = sum_k mean[k]*Wl[k][f] + hn[k]*Wr[k][f] + bias
        float o = bias;
#pragma unroll 8
        for (int k = 0; k < H_DIM; ++k) {
            float mk = __shfl(mean, k);
            float hk = __shfl(hn, k);
            o = fmaf(mk, Wl_s[k * COUT + li], o);
            o = fmaf(hk, Wr_s[k * COUT + li], o);
        }
        if (l >= COUT) o = 0.0f;

        // L2 row-norm across wave
        float nrm2 = o * o;
#pragma unroll
        for (int off = 32; off >= 1; off >>= 1) nrm2 += __shfl_xor(nrm2, off);
        float val = o / fmaxf(sqrtf(nrm2), 1e-12f);
        if (RELU) val = fmaxf(val, 0.0f);

        if (l < COUT) {
            if (FINAL) {
                if (isbf) ((__hip_bfloat16*)dout)[(size_t)n * COUT + l] = __float2bfloat16(val);
                else      ((float*)dout)[(size_t)n * COUT + l] = val;
            } else {
                h_out[(size_t)n * H_DIM + l] = __float2bfloat16(val);
            }
        }
    }
}

extern "C" void kernel_launch(void* const* d_in, const int* in_sizes, int n_in,
                              void* d_out, int out_size, void* d_ws, size_t ws_size,
                              hipStream_t stream)
{
    const void* x    = d_in[0];
    const void* ei   = d_in[1];
    const void* ew   = d_in[2];
    const void* embW = d_in[3];
    const void* embB = d_in[4];
    const void* Wl1 = d_in[5];  const void* bl1 = d_in[6];  const void* Wr1 = d_in[7];
    const void* Wl2 = d_in[8];  const void* bl2 = d_in[9];  const void* Wr2 = d_in[10];
    const void* Wl3 = d_in[11]; const void* bl3 = d_in[12]; const void* Wr3 = d_in[13];
    const void* Wl4 = d_in[14]; const void* bl4 = d_in[15]; const void* Wr4 = d_in[16];
    (void)in_sizes; (void)n_in; (void)out_size; (void)ws_size;

    char* ws = (char*)d_ws;
    size_t off = 0;
    auto alloc = [&](size_t bytes) -> void* {
        void* p = ws + off;
        off += (bytes + 255) & ~(size_t)255;
        return p;
    };
    __hip_bfloat16* h_a = (__hip_bfloat16*)alloc((size_t)N_NODES * H_DIM * 2);  // 12.8 MB
    __hip_bfloat16* h_b = (__hip_bfloat16*)alloc((size_t)N_NODES * H_DIM * 2);  // 12.8 MB
    int*   csr_src = (int*)  alloc((size_t)N_EDGES * sizeof(int));              // 12.8 MB
    float* csr_w   = (float*)alloc((size_t)N_EDGES * sizeof(float));            // 12.8 MB
    int*   deg     = (int*)  alloc((size_t)N_NODES * sizeof(int));
    int*   row_st  = (int*)  alloc((size_t)N_NODES * sizeof(int));
    int*   cursor  = (int*)  alloc((size_t)N_NODES * sizeof(int));
    float* inv_deg = (float*)alloc((size_t)N_NODES * sizeof(float));
    int*   total   = (int*)  alloc(256);
    int*   flags   = (int*)  alloc(256);

    const int NBn = (N_NODES + 255) / 256;   // 391
    const int NBe = (N_EDGES + 255) / 256;   // 12500

    detect_kernel<<<1, 64, 0, stream>>>(ei, x, flags);
    init_kernel<<<NBn, 256, 0, stream>>>(deg, total);
    deg_kernel<<<NBe, 256, 0, stream>>>(ei, deg, flags);
    rowstart_kernel<<<NBn, 256, 0, stream>>>(deg, row_st, cursor, inv_deg, total);
    fill_kernel<<<NBe, 256, 0, stream>>>(ei, ew, cursor, csr_src, csr_w, flags);
    embed_kernel<<<N_NODES, 64, 0, stream>>>(x, embW, embB, h_a, flags);

    sage_fused<H_DIM, true,  true,  false><<<2048, 256, 0, stream>>>(
        h_a, h_b, csr_src, csr_w, row_st, deg, inv_deg, Wl1, bl1, Wr1, flags, d_out);
    sage_fused<H_DIM, true,  true,  false><<<2048, 256, 0, stream>>>(
        h_b, h_a, csr_src, csr_w, row_st, deg, inv_deg, Wl2, bl2, Wr2, flags, d_out);
    sage_fused<H_DIM, true,  true,  false><<<2048, 256, 0, stream>>>(
        h_a, h_b, csr_src, csr_w, row_st, deg, inv_deg, Wl3, bl3, Wr3, flags, d_out);
    sage_fused<C_NUM, false, false, true ><<<2048, 256, 0, stream>>>(
        h_b, h_a, csr_src, csr_w, row_st, deg, inv_deg, Wl4, bl4, Wr4, flags, d_out);
}

// Round 4
// 987.337 us; speedup vs baseline: 4.3058x; 2.1221x over previous
//
#include <hip/hip_runtime.h>
#include <hip/hip_bf16.h>

#define N_NODES 100000
#define N_EDGES 3200000
#define F_IN    100
#define H_DIM   64
#define C_NUM   18

typedef __attribute__((ext_vector_type(8))) short short8;
typedef __attribute__((ext_vector_type(4))) float f32x4;

// ---- dtype-flexible loads (flags decided at runtime by detect_kernel) ----
__device__ __forceinline__ float ldf(const void* p, long long i, int isbf) {
    if (isbf) return __bfloat162float(((const __hip_bfloat16*)p)[i]);
    return ((const float*)p)[i];
}
__device__ __forceinline__ int ldi(const void* p, long long i, int is64) {
    if (is64) return (int)(((const long long*)p)[i]);
    return ((const int*)p)[i];
}
__device__ __forceinline__ float us2f(unsigned short u) {
    return __uint_as_float(((unsigned int)u) << 16);
}
__device__ __forceinline__ unsigned short f2us(float f) {
    __hip_bfloat16 b = __float2bfloat16(f);
    return *(unsigned short*)&b;
}

// ---- probe input dtypes; write flags ----
__global__ void detect_kernel(const void* ei, const void* x, int* flags)
{
    if (threadIdx.x != 0 || blockIdx.x != 0) return;
    const long long* e64 = (const long long*)ei;
    int ok64 = 1;
    for (int i = 0; i < 128; ++i) {
        long long v = e64[i];
        if (v < 0 || v >= N_NODES) { ok64 = 0; break; }
    }
    const __hip_bfloat16* xb = (const __hip_bfloat16*)x;
    int cnt = 0;
    for (int i = 0; i < 256; ++i) {
        float v = fabsf(__bfloat162float(xb[i]));
        if (v == 0.0f || (v > 9.5367431640625e-7f && v < 1.0e6f)) ++cnt;
    }
    flags[0] = ok64;
    flags[1] = (cnt >= 240) ? 1 : 0;
}

__global__ void init_kernel(int* __restrict__ deg, int* __restrict__ total)
{
    int i = blockIdx.x * blockDim.x + threadIdx.x;
    if (i < N_NODES) deg[i] = 0;
    if (i == 0) *total = 0;
}

__global__ void deg_kernel(const void* ei, int* __restrict__ deg, const int* __restrict__ flags)
{
    long long e = (long long)blockIdx.x * blockDim.x + threadIdx.x;
    if (e >= N_EDGES) return;
    int d = ldi(ei, (long long)N_EDGES + e, flags[0]);
    atomicAdd(&deg[d], 1);
}

// ---- assign CSR segments: wave prefix sum + one atomic per wave ----
__global__ void rowstart_kernel(const int* __restrict__ deg,
                                int* __restrict__ row_start,
                                int* __restrict__ cursor,
                                float* __restrict__ inv_deg,
                                int* __restrict__ total)
{
    const int i = blockIdx.x * blockDim.x + threadIdx.x;
    const int l = threadIdx.x & 63;
    const int d = (i < N_NODES) ? deg[i] : 0;
    int incl = d;
#pragma unroll
    for (int off = 1; off < 64; off <<= 1) {
        int v = __shfl_up(incl, off);
        if (l >= off) incl += v;
    }
    const int wave_total = __shfl(incl, 63);
    int base = 0;
    if (l == 63) base = atomicAdd(total, wave_total);
    base = __shfl(base, 63);
    if (i < N_NODES) {
        int rs = base + incl - d;
        row_start[i] = rs;
        cursor[i]    = rs;
        inv_deg[i]   = 1.0f / (float)max(d, 1);
    }
}

__global__ void fill_kernel(const void* ei, const void* ew,
                            int* __restrict__ cursor,
                            int* __restrict__ csr_src, __hip_bfloat16* __restrict__ csr_w,
                            const int* __restrict__ flags)
{
    long long e = (long long)blockIdx.x * blockDim.x + threadIdx.x;
    if (e >= N_EDGES) return;
    const int is64 = flags[0];
    int s = ldi(ei, e, is64);
    int d = ldi(ei, (long long)N_EDGES + e, is64);
    int pos = atomicAdd(&cursor[d], 1);
    csr_src[pos] = s;
    csr_w[pos]   = __float2bfloat16(ldf(ew, e, flags[1]));
}

// ---- embedding via MFMA: h = relu(x @ W + b), [N,100pad128] @ [128,64] ----
__global__ void embed_mfma(const void* x, const void* W, const void* b,
                           __hip_bfloat16* __restrict__ h, const int* __restrict__ flags)
{
    constexpr int KP = 136;                 // padded K stride (shorts); 272B = 17*16B
    __shared__ unsigned short W_s[H_DIM * KP];
    __shared__ float b_s[H_DIM];
    const int t = threadIdx.x;
    const int isbf = flags[1];
    for (int i = t; i < 128 * H_DIM; i += 256) {
        int k = i >> 6, n = i & 63;
        float v = (k < F_IN) ? ldf(W, (long long)k * H_DIM + n, isbf) : 0.0f;
        W_s[n * KP + k] = f2us(v);
    }
    if (t < H_DIM) b_s[t] = ldf(b, t, isbf);
    __syncthreads();

    const int wave = t >> 6, lane = t & 63, c = lane & 15, quad = lane >> 4;
    short8 bfrag[4][4];
#pragma unroll
    for (int nt = 0; nt < 4; ++nt)
#pragma unroll
        for (int kt = 0; kt < 4; ++kt)
            bfrag[nt][kt] = *(const short8*)&W_s[(nt * 16 + c) * KP + kt * 32 + quad * 8];

    const int nb = (blockIdx.x * 4 + wave) * 16;
    if (nb >= N_NODES) return;
    int node = nb + c; if (node >= N_NODES) node = N_NODES - 1;

    short8 afrag[4];
#pragma unroll
    for (int kt = 0; kt < 4; ++kt) {
        short8 a;
#pragma unroll
        for (int j = 0; j < 8; ++j) {
            int k = kt * 32 + quad * 8 + j;
            float v = (k < F_IN) ? ldf(x, (long long)node * F_IN + k, isbf) : 0.0f;
            a[j] = (short)f2us(v);
        }
        afrag[kt] = a;
    }

    f32x4 acc[4] = {};
#pragma unroll
    for (int nt = 0; nt < 4; ++nt)
#pragma unroll
        for (int kt = 0; kt < 4; ++kt)
            acc[nt] = __builtin_amdgcn_mfma_f32_16x16x32_bf16(afrag[kt], bfrag[nt][kt], acc[nt], 0, 0, 0);

#pragma unroll
    for (int nt = 0; nt < 4; ++nt)
#pragma unroll
        for (int reg = 0; reg < 4; ++reg) {
            int row = quad * 4 + reg;
            int nn  = nb + row;
            int col = nt * 16 + c;
            if (nn < N_NODES) {
                float v = fmaxf(acc[nt][reg] + b_s[col], 0.0f);
                h[(size_t)nn * H_DIM + col] = __float2bfloat16(v);
            }
        }
}

// ---- gather: mean[n] = inv_deg * sum_j w_j * h[src_j], wave/node, 4 nbrs/iter ----
template <bool USE_W>
__global__ void gather_mean(const __hip_bfloat16* __restrict__ h,
                            const int* __restrict__ csr_src,
                            const __hip_bfloat16* __restrict__ csr_w,
                            const int* __restrict__ row_start,
                            const int* __restrict__ deg,
                            const float* __restrict__ inv_deg,
                            __hip_bfloat16* __restrict__ mean)
{
    const int lane = threadIdx.x & 63;
    const int c = lane & 15;        // feature quad: features 4c..4c+3
    const int r = lane >> 4;        // neighbor sub-index 0..3
    const int wid = blockIdx.x * 4 + (threadIdx.x >> 6);
    const int nw  = gridDim.x * 4;

    for (int n = wid; n < N_NODES; n += nw) {
        const int start = row_start[n];
        const int d = deg[n];
        float a0 = 0.f, a1 = 0.f, a2 = 0.f, a3 = 0.f;
        for (int j0 = 0; j0 < d; j0 += 4) {
            int j = j0 + r;
            bool valid = (j < d);
            int idx = start + (valid ? j : (d - 1));
            int s = csr_src[idx];
            float w = 1.0f;
            if (USE_W) w = us2f(((const unsigned short*)csr_w)[idx]);
            if (!valid) w = 0.0f;
            uint2 hv = *(const uint2*)(h + (size_t)s * H_DIM + 4 * c);
            a0 = fmaf(w, us2f((unsigned short)(hv.x & 0xffff)), a0);
            a1 = fmaf(w, us2f((unsigned short)(hv.x >> 16)),    a1);
            a2 = fmaf(w, us2f((unsigned short)(hv.y & 0xffff)), a2);
            a3 = fmaf(w, us2f((unsigned short)(hv.y >> 16)),    a3);
        }
        a0 += __shfl_xor(a0, 16); a0 += __shfl_xor(a0, 32);
        a1 += __shfl_xor(a1, 16); a1 += __shfl_xor(a1, 32);
        a2 += __shfl_xor(a2, 16); a2 += __shfl_xor(a2, 32);
        a3 += __shfl_xor(a3, 16); a3 += __shfl_xor(a3, 32);
        if (r == 0) {
            float inv = inv_deg[n];
            uint2 st;
            st.x = (unsigned)f2us(a0 * inv) | ((unsigned)f2us(a1 * inv) << 16);
            st.y = (unsigned)f2us(a2 * inv) | ((unsigned)f2us(a3 * inv) << 16);
            *(uint2*)(mean + (size_t)n * H_DIM + 4 * c) = st;
        }
    }
}

// ---- transform via MFMA: out = L2norm([mean|h] @ [Wl;Wr] + b), opt relu ----
// h_out may alias meanp: each wave reads its own 16 rows into regs before writing.
template <int COUT, bool RELU, bool FINAL>
__global__ void transform_mfma(const __hip_bfloat16* __restrict__ meanp,
                               const __hip_bfloat16* __restrict__ hp,
                               const void* Wl, const void* bl, const void* Wr,
                               __hip_bfloat16* __restrict__ h_out,
                               const int* __restrict__ flags, void* dout)
{
    constexpr int CP = (COUT + 15) & ~15;   // 64 or 32
    constexpr int NT = CP / 16;             // 4 or 2
    constexpr int KP = 136;
    __shared__ unsigned short W_s[CP * KP];
    __shared__ float b_s[CP];
    const int t = threadIdx.x;
    const int isbf = flags[1];
    for (int i = t; i < 128 * CP; i += 256) {
        int k = i / CP, n = i % CP;
        float v = 0.0f;
        if (n < COUT)
            v = (k < 64) ? ldf(Wl, (long long)k * COUT + n, isbf)
                         : ldf(Wr, (long long)(k - 64) * COUT + n, isbf);
        W_s[n * KP + k] = f2us(v);
    }
    if (t < CP) b_s[t] = (t < COUT) ? ldf(bl, t, isbf) : 0.0f;
    __syncthreads();

    const int wave = t >> 6, lane = t & 63, c = lane & 15, quad = lane >> 4;
    short8 bfrag[NT][4];
#pragma unroll
    for (int nt = 0; nt < NT; ++nt)
#pragma unroll
        for (int kt = 0; kt < 4; ++kt)
            bfrag[nt][kt] = *(const short8*)&W_s[(nt * 16 + c) * KP + kt * 32 + quad * 8];

    const int nb = (blockIdx.x * 4 + wave) * 16;
    if (nb >= N_NODES) return;
    int node = nb + c; if (node >= N_NODES) node = N_NODES - 1;

    short8 afrag[4];
#pragma unroll
    for (int kt = 0; kt < 4; ++kt) {
        const __hip_bfloat16* sp = (kt < 2) ? meanp : hp;
        afrag[kt] = *(const short8*)(sp + (size_t)node * H_DIM + (kt & 1) * 32 + quad * 8);
    }

    f32x4 acc[NT] = {};
#pragma unroll
    for (int nt = 0; nt < NT; ++nt)
#pragma unroll
        for (int kt = 0; kt < 4; ++kt)
            acc[nt] = __builtin_amdgcn_mfma_f32_16x16x32_bf16(afrag[kt], bfrag[nt][kt], acc[nt], 0, 0, 0);

    // add bias, then L2-norm per row (row = quad*4+reg spans cols across nt,lanes)
    float rs[4];
#pragma unroll
    for (int reg = 0; reg < 4; ++reg) {
        float s2 = 0.f;
#pragma unroll
        for (int nt = 0; nt < NT; ++nt) {
            float v = acc[nt][reg] + b_s[nt * 16 + c];
            acc[nt][reg] = v;
            s2 += v * v;
        }
        s2 += __shfl_xor(s2, 1); s2 += __shfl_xor(s2, 2);
        s2 += __shfl_xor(s2, 4); s2 += __shfl_xor(s2, 8);
        rs[reg] = 1.0f / fmaxf(sqrtf(s2), 1e-12f);
    }

#pragma unroll
    for (int nt = 0; nt < NT; ++nt)
#pragma unroll
        for (int reg = 0; reg < 4; ++reg) {
            int row = quad * 4 + reg;
            int nn  = nb + row;
            int col = nt * 16 + c;
            if (nn < N_NODES && col < COUT) {
                float v = acc[nt][reg] * rs[reg];
                if (RELU) v = fmaxf(v, 0.0f);
                if (FINAL) {
                    if (isbf) ((__hip_bfloat16*)dout)[(size_t)nn * COUT + col] = __float2bfloat16(v);
                    else      ((float*)dout)[(size_t)nn * COUT + col] = v;
                } else {
                    h_out[(size_t)nn * H_DIM + col] = __float2bfloat16(v);
                }
            }
        }
}

extern "C" void kernel_launch(void* const* d_in, const int* in_sizes, int n_in,
                              void* d_out, int out_size, void* d_ws, size_t ws_size,
                              hipStream_t stream)
{
    const void* x    = d_in[0];
    const void* ei   = d_in[1];
    const void* ew   = d_in[2];
    const void* embW = d_in[3];
    const void* embB = d_in[4];
    const void* Wl1 = d_in[5];  const void* bl1 = d_in[6];  const void* Wr1 = d_in[7];
    const void* Wl2 = d_in[8];  const void* bl2 = d_in[9];  const void* Wr2 = d_in[10];
    const void* Wl3 = d_in[11]; const void* bl3 = d_in[12]; const void* Wr3 = d_in[13];
    const void* Wl4 = d_in[14]; const void* bl4 = d_in[15]; const void* Wr4 = d_in[16];
    (void)in_sizes; (void)n_in; (void)out_size; (void)ws_size;

    char* ws = (char*)d_ws;
    size_t off = 0;
    auto alloc = [&](size_t bytes) -> void* {
        void* p = ws + off;
        off += (bytes + 255) & ~(size_t)255;
        return p;
    };
    __hip_bfloat16* hA = (__hip_bfloat16*)alloc((size_t)N_NODES * H_DIM * 2);   // 12.8 MB
    __hip_bfloat16* hB = (__hip_bfloat16*)alloc((size_t)N_NODES * H_DIM * 2);   // 12.8 MB
    int*            csr_src = (int*)alloc((size_t)N_EDGES * sizeof(int));       // 12.8 MB
    __hip_bfloat16* csr_w   = (__hip_bfloat16*)alloc((size_t)N_EDGES * 2);      //  6.4 MB
    int*   deg     = (int*)  alloc((size_t)N_NODES * sizeof(int));
    int*   row_st  = (int*)  alloc((size_t)N_NODES * sizeof(int));
    int*   cursor  = (int*)  alloc((size_t)N_NODES * sizeof(int));
    float* inv_deg = (float*)alloc((size_t)N_NODES * sizeof(float));
    int*   total   = (int*)  alloc(256);
    int*   flags   = (int*)  alloc(256);

    const int NBn = (N_NODES + 255) / 256;
    const int NBe = (N_EDGES + 255) / 256;
    const int NBt = (N_NODES + 63) / 64;    // 1563 blocks of 4 waves x 16 nodes

    detect_kernel<<<1, 64, 0, stream>>>(ei, x, flags);
    init_kernel<<<NBn, 256, 0, stream>>>(deg, total);
    deg_kernel<<<NBe, 256, 0, stream>>>(ei, deg, flags);
    rowstart_kernel<<<NBn, 256, 0, stream>>>(deg, row_st, cursor, inv_deg, total);
    fill_kernel<<<NBe, 256, 0, stream>>>(ei, ew, cursor, csr_src, csr_w, flags);
    embed_mfma<<<NBt, 256, 0, stream>>>(x, embW, embB, hA, flags);

    // layer 1: h=A  → mean in B, out overwrites B
    gather_mean<true><<<2048, 256, 0, stream>>>(hA, csr_src, csr_w, row_st, deg, inv_deg, hB);
    transform_mfma<H_DIM, true, false><<<NBt, 256, 0, stream>>>(
        hB, hA, Wl1, bl1, Wr1, hB, flags, d_out);
    // layer 2: h=B → mean in A, out overwrites A
    gather_mean<true><<<2048, 256, 0, stream>>>(hB, csr_src, csr_w, row_st, deg, inv_deg, hA);
    transform_mfma<H_DIM, true, false><<<NBt, 256, 0, stream>>>(
        hA, hB, Wl2, bl2, Wr2, hA, flags, d_out);
    // layer 3: h=A → mean in B, out overwrites B
    gather_mean<true><<<2048, 256, 0, stream>>>(hA, csr_src, csr_w, row_st, deg, inv_deg, hB);
    transform_mfma<H_DIM, true, false><<<NBt, 256, 0, stream>>>(
        hB, hA, Wl3, bl3, Wr3, hB, flags, d_out);
    // layer 4: h=B → mean in A (unweighted), out → d_out
    gather_mean<false><<<2048, 256, 0, stream>>>(hB, csr_src, csr_w, row_st, deg, inv_deg, hA);
    transform_mfma<C_NUM, false, true><<<NBt, 256, 0, stream>>>(
        hA, hB, Wl4, bl4, Wr4, nullptr, flags, d_out);
}

// Round 5
// 844.030 us; speedup vs baseline: 5.0369x; 1.1698x over previous
//
#include <hip/hip_runtime.h>
#include <hip/hip_bf16.h>

#define N_NODES   100000
#define N_EDGES   3200000
#define F_IN      100
#define H_DIM     64
#define C_NUM     18
#define N_BUCKET  6250      // 16 nodes per bucket, exactly 100000/16

typedef __attribute__((ext_vector_type(8))) short short8;
typedef __attribute__((ext_vector_type(4))) float f32x4;

// ---- dtype-flexible loads (flags decided at runtime by detect_kernel) ----
__device__ __forceinline__ float ldf(const void* p, long long i, int isbf) {
    if (isbf) return __bfloat162float(((const __hip_bfloat16*)p)[i]);
    return ((const float*)p)[i];
}
__device__ __forceinline__ int ldi(const void* p, long long i, int is64) {
    if (is64) return (int)(((const long long*)p)[i]);
    return ((const int*)p)[i];
}
__device__ __forceinline__ unsigned short f2us(float f) {
    __hip_bfloat16 b = __float2bfloat16(f);
    return *(unsigned short*)&b;
}

// ---- probe input dtypes; write flags ----
__global__ void detect_kernel(const void* ei, const void* x, int* flags)
{
    if (threadIdx.x != 0 || blockIdx.x != 0) return;
    const long long* e64 = (const long long*)ei;
    int ok64 = 1;
    for (int i = 0; i < 128; ++i) {
        long long v = e64[i];
        if (v < 0 || v >= N_NODES) { ok64 = 0; break; }
    }
    const __hip_bfloat16* xb = (const __hip_bfloat16*)x;
    int cnt = 0;
    for (int i = 0; i < 256; ++i) {
        float v = fabsf(__bfloat162float(xb[i]));
        if (v == 0.0f || (v > 9.5367431640625e-7f && v < 1.0e6f)) ++cnt;
    }
    flags[0] = ok64;
    flags[1] = (cnt >= 240) ? 1 : 0;
}

__global__ void zero_buckets(int* __restrict__ bcnt)
{
    int i = blockIdx.x * blockDim.x + threadIdx.x;
    if (i < N_BUCKET) bcnt[i] = 0;
}

// ---- pass A: bucket sizes (bucket = dst >> 4) ----
__global__ void bucket_count(const void* ei, int* __restrict__ bcnt,
                             const int* __restrict__ flags)
{
    int e = blockIdx.x * blockDim.x + threadIdx.x;
    if (e >= N_EDGES) return;
    int d = ldi(ei, (long long)N_EDGES + e, flags[0]);
    atomicAdd(&bcnt[d >> 4], 1);
}

// ---- prefix scan over bucket counts (single block) ----
__global__ void scan_kernel(const int* __restrict__ cnt, int* __restrict__ base,
                            int* __restrict__ cursor)
{
    __shared__ int tmp[1024];
    __shared__ int carry_s;
    const int t = threadIdx.x;
    if (t == 0) carry_s = 0;
    __syncthreads();
    for (int c0 = 0; c0 < N_BUCKET; c0 += 1024) {
        int i = c0 + t;
        int v = (i < N_BUCKET) ? cnt[i] : 0;
        tmp[t] = v;
        __syncthreads();
        for (int off = 1; off < 1024; off <<= 1) {
            int add = (t >= off) ? tmp[t - off] : 0;
            __syncthreads();
            tmp[t] += add;
            __syncthreads();
        }
        int carry = carry_s;
        int excl  = carry + tmp[t] - v;
        if (i < N_BUCKET) { base[i] = excl; cursor[i] = excl; }
        int tot = tmp[1023];
        __syncthreads();
        if (t == 0) carry_s = carry + tot;
        __syncthreads();
    }
    if (t == 0) base[N_BUCKET] = carry_s;   // == N_EDGES
}

// ---- pass B: scatter edges into contiguous bucket regions ----
__global__ void bucket_scatter(const void* ei, const void* ew,
                               int* __restrict__ cursor, uint2* __restrict__ temp,
                               const int* __restrict__ flags)
{
    int e = blockIdx.x * blockDim.x + threadIdx.x;
    if (e >= N_EDGES) return;
    const int is64 = flags[0];
    int s = ldi(ei, e, is64);
    int d = ldi(ei, (long long)N_EDGES + e, is64);
    float w = ldf(ew, e, flags[1]);
    int pos = atomicAdd(&cursor[d >> 4], 1);
    uint2 v;
    v.x = (unsigned)s | ((unsigned)(d & 15) << 17);   // src:17b | dst-low:4b
    v.y = (unsigned)f2us(w);
    temp[pos] = v;
}

// ---- pass C: per-bucket CSR finalize; also writes deg/row_start/inv_deg ----
// csr entry: src:17b | bf16-weight-without-sign:15b (weights >= 0)
__global__ void csr_build(const uint2* __restrict__ temp,
                          const int* __restrict__ bbase,
                          unsigned int* __restrict__ csr_pk,
                          int* __restrict__ deg, int* __restrict__ row_start,
                          float* __restrict__ inv_deg)
{
    __shared__ int cnt[16], base_s[16], cur[16];
    const int b = blockIdx.x;
    const int t = threadIdx.x;
    if (t < 16) cnt[t] = 0;
    __syncthreads();
    const int bs = bbase[b], be = bbase[b + 1];
    for (int i = bs + t; i < be; i += 256)
        atomicAdd(&cnt[(temp[i].x >> 17) & 15], 1);
    __syncthreads();
    if (t == 0) {
        int run = bs;
        for (int k = 0; k < 16; ++k) { base_s[k] = run; run += cnt[k]; }
    }
    __syncthreads();
    if (t < 16) {
        cur[t] = base_s[t];
        int node = b * 16 + t;     // N_NODES is exactly 16*N_BUCKET
        deg[node]       = cnt[t];
        row_start[node] = base_s[t];
        inv_deg[node]   = 1.0f / (float)max(cnt[t], 1);
    }
    __syncthreads();
    for (int i = bs + t; i < be; i += 256) {
        uint2 e = temp[i];
        int k = (e.x >> 17) & 15;
        int pos = atomicAdd(&cur[k], 1);
        csr_pk[pos] = (e.x & 0x1FFFFu) | ((e.y & 0x7FFFu) << 17);
    }
}

// ---- embedding via MFMA: h = relu(x @ W + b), [N,100pad128] @ [128,64] ----
__global__ void embed_mfma(const void* x, const void* W, const void* b,
                           __hip_bfloat16* __restrict__ h, const int* __restrict__ flags)
{
    constexpr int KP = 136;
    __shared__ unsigned short W_s[H_DIM * KP];
    __shared__ float b_s[H_DIM];
    const int t = threadIdx.x;
    const int isbf = flags[1];
    for (int i = t; i < 128 * H_DIM; i += 256) {
        int k = i >> 6, n = i & 63;
        float v = (k < F_IN) ? ldf(W, (long long)k * H_DIM + n, isbf) : 0.0f;
        W_s[n * KP + k] = f2us(v);
    }
    if (t < H_DIM) b_s[t] = ldf(b, t, isbf);
    __syncthreads();

    const int wave = t >> 6, lane = t & 63, c = lane & 15, quad = lane >> 4;
    short8 bfrag[4][4];
#pragma unroll
    for (int nt = 0; nt < 4; ++nt)
#pragma unroll
        for (int kt = 0; kt < 4; ++kt)
            bfrag[nt][kt] = *(const short8*)&W_s[(nt * 16 + c) * KP + kt * 32 + quad * 8];

    const int nb = (blockIdx.x * 4 + wave) * 16;
    if (nb >= N_NODES) return;
    int node = nb + c; if (node >= N_NODES) node = N_NODES - 1;

    short8 afrag[4];
#pragma unroll
    for (int kt = 0; kt < 4; ++kt) {
        short8 a;
#pragma unroll
        for (int j = 0; j < 8; ++j) {
            int k = kt * 32 + quad * 8 + j;
            float v = (k < F_IN) ? ldf(x, (long long)node * F_IN + k, isbf) : 0.0f;
            a[j] = (short)f2us(v);
        }
        afrag[kt] = a;
    }

    f32x4 acc[4] = {};
#pragma unroll
    for (int nt = 0; nt < 4; ++nt)
#pragma unroll
        for (int kt = 0; kt < 4; ++kt)
            acc[nt] = __builtin_amdgcn_mfma_f32_16x16x32_bf16(afrag[kt], bfrag[nt][kt], acc[nt], 0, 0, 0);

#pragma unroll
    for (int nt = 0; nt < 4; ++nt)
#pragma unroll
        for (int reg = 0; reg < 4; ++reg) {
            int nn = nb + quad * 4 + reg;
            int col = nt * 16 + c;
            if (nn < N_NODES) {
                float v = fmaxf(acc[nt][reg] + b_s[col], 0.0f);
                h[(size_t)nn * H_DIM + col] = __float2bfloat16(v);
            }
        }
}

// ---- gather: mean[n] = inv_deg * sum_j w_j * h[src_j], wave per node ----
// lane = (r,c): r = neighbor sub-index (4), c = feature quad (16 x 4 features)
template <bool USE_W>
__global__ void gather_mean(const __hip_bfloat16* __restrict__ h,
                            const unsigned int* __restrict__ csr_pk,
                            const int* __restrict__ row_start,
                            const int* __restrict__ deg,
                            const float* __restrict__ inv_deg,
                            __hip_bfloat16* __restrict__ mean)
{
    const int lane = threadIdx.x & 63;
    const int c = lane & 15;
    const int r = lane >> 4;
    const int wid = blockIdx.x * 4 + (threadIdx.x >> 6);
    const int nw  = gridDim.x * 4;

    for (int n = wid; n < N_NODES; n += nw) {
        const int start = row_start[n];
        const int d     = deg[n];
        // cooperative load: 64 lanes grab first 64 packed entries in one shot
        unsigned int ev = 0;
        if (lane < d) ev = csr_pk[start + lane];
        const int dmain = min(d, 64);
        float a0 = 0.f, a1 = 0.f, a2 = 0.f, a3 = 0.f;
#pragma unroll 4
        for (int j0 = 0; j0 < dmain; j0 += 4) {
            unsigned int e = __shfl(ev, j0 + r);
            int s = e & 0x1FFFF;                 // invalid lanes: ev=0 -> s=0, w=0
            float w;
            if (USE_W) w = __uint_as_float((e & 0xFFFE0000u) >> 1);
            else       w = (j0 + r < dmain) ? 1.0f : 0.0f;
            uint2 hv = *(const uint2*)(h + (size_t)s * H_DIM + 4 * c);
            a0 = fmaf(w, __uint_as_float(hv.x << 16),          a0);
            a1 = fmaf(w, __uint_as_float(hv.x & 0xFFFF0000u),  a1);
            a2 = fmaf(w, __uint_as_float(hv.y << 16),          a2);
            a3 = fmaf(w, __uint_as_float(hv.y & 0xFFFF0000u),  a3);
        }
        // rare tail (deg > 64): direct loads
        for (int j = 64 + r; j < d; j += 4) {
            unsigned int e = csr_pk[start + j];
            int s = e & 0x1FFFF;
            float w = USE_W ? __uint_as_float((e & 0xFFFE0000u) >> 1) : 1.0f;
            uint2 hv = *(const uint2*)(h + (size_t)s * H_DIM + 4 * c);
            a0 = fmaf(w, __uint_as_float(hv.x << 16),          a0);
            a1 = fmaf(w, __uint_as_float(hv.x & 0xFFFF0000u),  a1);
            a2 = fmaf(w, __uint_as_float(hv.y << 16),          a2);
            a3 = fmaf(w, __uint_as_float(hv.y & 0xFFFF0000u),  a3);
        }
        a0 += __shfl_xor(a0, 16); a0 += __shfl_xor(a0, 32);
        a1 += __shfl_xor(a1, 16); a1 += __shfl_xor(a1, 32);
        a2 += __shfl_xor(a2, 16); a2 += __shfl_xor(a2, 32);
        a3 += __shfl_xor(a3, 16); a3 += __shfl_xor(a3, 32);
        if (r == 0) {
            float inv = inv_deg[n];
            uint2 st;
            st.x = (unsigned)f2us(a0 * inv) | ((unsigned)f2us(a1 * inv) << 16);
            st.y = (unsigned)f2us(a2 * inv) | ((unsigned)f2us(a3 * inv) << 16);
            *(uint2*)(mean + (size_t)n * H_DIM + 4 * c) = st;
        }
    }
}

// ---- transform via MFMA: out = L2norm([mean|h] @ [Wl;Wr] + b), opt relu ----
template <int COUT, bool RELU, bool FINAL>
__global__ void transform_mfma(const __hip_bfloat16* __restrict__ meanp,
                               const __hip_bfloat16* __restrict__ hp,
                               const void* Wl, const void* bl, const void* Wr,
                               __hip_bfloat16* __restrict__ h_out,
                               const int* __restrict__ flags, void* dout)
{
    constexpr int CP = (COUT + 15) & ~15;
    constexpr int NT = CP / 16;
    constexpr int KP = 136;
    __shared__ unsigned short W_s[CP * KP];
    __shared__ float b_s[CP];
    const int t = threadIdx.x;
    const int isbf = flags[1];
    for (int i = t; i < 128 * CP; i += 256) {
        int k = i / CP, n = i % CP;
        float v = 0.0f;
        if (n < COUT)
            v = (k < 64) ? ldf(Wl, (long long)k * COUT + n, isbf)
                         : ldf(Wr, (long long)(k - 64) * COUT + n, isbf);
        W_s[n * KP + k] = f2us(v);
    }
    if (t < CP) b_s[t] = (t < COUT) ? ldf(bl, t, isbf) : 0.0f;
    __syncthreads();

    const int wave = t >> 6, lane = t & 63, c = lane & 15, quad = lane >> 4;
    short8 bfrag[NT][4];
#pragma unroll
    for (int nt = 0; nt < NT; ++nt)
#pragma unroll
        for (int kt = 0; kt < 4; ++kt)
            bfrag[nt][kt] = *(const short8*)&W_s[(nt * 16 + c) * KP + kt * 32 + quad * 8];

    const int nb = (blockIdx.x * 4 + wave) * 16;
    if (nb >= N_NODES) return;
    int node = nb + c; if (node >= N_NODES) node = N_NODES - 1;

    short8 afrag[4];
#pragma unroll
    for (int kt = 0; kt < 4; ++kt) {
        const __hip_bfloat16* sp = (kt < 2) ? meanp : hp;
        afrag[kt] = *(const short8*)(sp + (size_t)node * H_DIM + (kt & 1) * 32 + quad * 8);
    }

    f32x4 acc[NT] = {};
#pragma unroll
    for (int nt = 0; nt < NT; ++nt)
#pragma unroll
        for (int kt = 0; kt < 4; ++kt)
            acc[nt] = __builtin_amdgcn_mfma_f32_16x16x32_bf16(afrag[kt], bfrag[nt][kt], acc[nt], 0, 0, 0);

    float rs[4];
#pragma unroll
    for (int reg = 0; reg < 4; ++reg) {
        float s2 = 0.f;
#pragma unroll
        for (int nt = 0; nt < NT; ++nt) {
            float v = acc[nt][reg] + b_s[nt * 16 + c];
            acc[nt][reg] = v;
            s2 += v * v;
        }
        s2 += __shfl_xor(s2, 1); s2 += __shfl_xor(s2, 2);
        s2 += __shfl_xor(s2, 4); s2 += __shfl_xor(s2, 8);
        rs[reg] = 1.0f / fmaxf(sqrtf(s2), 1e-12f);
    }

#pragma unroll
    for (int nt = 0; nt < NT; ++nt)
#pragma unroll
        for (int reg = 0; reg < 4; ++reg) {
            int nn  = nb + quad * 4 + reg;
            int col = nt * 16 + c;
            if (nn < N_NODES && col < COUT) {
                float v = acc[nt][reg] * rs[reg];
                if (RELU) v = fmaxf(v, 0.0f);
                if (FINAL) {
                    if (isbf) ((__hip_bfloat16*)dout)[(size_t)nn * COUT + col] = __float2bfloat16(v);
                    else      ((float*)dout)[(size_t)nn * COUT + col] = v;
                } else {
                    h_out[(size_t)nn * H_DIM + col] = __float2bfloat16(v);
                }
            }
        }
}

extern "C" void kernel_launch(void* const* d_in, const int* in_sizes, int n_in,
                              void* d_out, int out_size, void* d_ws, size_t ws_size,
                              hipStream_t stream)
{
    const void* x    = d_in[0];
    const void* ei   = d_in[1];
    const void* ew   = d_in[2];
    const void* embW = d_in[3];
    const void* embB = d_in[4];
    const void* Wl1 = d_in[5];  const void* bl1 = d_in[6];  const void* Wr1 = d_in[7];
    const void* Wl2 = d_in[8];  const void* bl2 = d_in[9];  const void* Wr2 = d_in[10];
    const void* Wl3 = d_in[11]; const void* bl3 = d_in[12]; const void* Wr3 = d_in[13];
    const void* Wl4 = d_in[14]; const void* bl4 = d_in[15]; const void* Wr4 = d_in[16];
    (void)in_sizes; (void)n_in; (void)out_size; (void)ws_size;

    char* ws = (char*)d_ws;
    size_t off = 0;
    auto alloc = [&](size_t bytes) -> void* {
        void* p = ws + off;
        off += (bytes + 255) & ~(size_t)255;
        return p;
    };
    // temp (edge staging, 25.6 MB) is dead after csr_build; hA/hB alias it
    // because embed/gather/transform all run after csr_build on the stream.
    uint2* temp = (uint2*)alloc((size_t)N_EDGES * sizeof(uint2));
    __hip_bfloat16* hA = (__hip_bfloat16*)temp;
    __hip_bfloat16* hB = (__hip_bfloat16*)((char*)temp + (size_t)N_NODES * H_DIM * 2);
    unsigned int* csr_pk = (unsigned int*)alloc((size_t)N_EDGES * sizeof(unsigned int));
    int*   bcnt    = (int*)  alloc((N_BUCKET)     * sizeof(int));
    int*   bbase   = (int*)  alloc((N_BUCKET + 1) * sizeof(int));
    int*   bcursor = (int*)  alloc((N_BUCKET)     * sizeof(int));
    int*   deg     = (int*)  alloc((size_t)N_NODES * sizeof(int));
    int*   row_st  = (int*)  alloc((size_t)N_NODES * sizeof(int));
    float* inv_deg = (float*)alloc((size_t)N_NODES * sizeof(float));
    int*   flags   = (int*)  alloc(256);

    const int NBe = (N_EDGES + 255) / 256;     // 12500
    const int NBb = (N_BUCKET + 255) / 256;    // 25
    const int NBt = (N_NODES + 63) / 64;       // 1563

    detect_kernel<<<1, 64, 0, stream>>>(ei, x, flags);
    zero_buckets<<<NBb, 256, 0, stream>>>(bcnt);
    bucket_count<<<NBe, 256, 0, stream>>>(ei, bcnt, flags);
    scan_kernel<<<1, 1024, 0, stream>>>(bcnt, bbase, bcursor);
    bucket_scatter<<<NBe, 256, 0, stream>>>(ei, ew, bcursor, temp, flags);
    csr_build<<<N_BUCKET, 256, 0, stream>>>(temp, bbase, csr_pk, deg, row_st, inv_deg);

    embed_mfma<<<NBt, 256, 0, stream>>>(x, embW, embB, hA, flags);

    // layer 1: h=A -> mean in B, out overwrites B
    gather_mean<true><<<2048, 256, 0, stream>>>(hA, csr_pk, row_st, deg, inv_deg, hB);
    transform_mfma<H_DIM, true, false><<<NBt, 256, 0, stream>>>(
        hB, hA, Wl1, bl1, Wr1, hB, flags, d_out);
    // layer 2: h=B -> mean in A, out overwrites A
    gather_mean<true><<<2048, 256, 0, stream>>>(hB, csr_pk, row_st, deg, inv_deg, hA);
    transform_mfma<H_DIM, true, false><<<NBt, 256, 0, stream>>>(
        hA, hB, Wl2, bl2, Wr2, hA, flags, d_out);
    // layer 3: h=A -> mean in B, out overwrites B
    gather_mean<true><<<2048, 256, 0, stream>>>(hA, csr_pk, row_st, deg, inv_deg, hB);
    transform_mfma<H_DIM, true, false><<<NBt, 256, 0, stream>>>(
        hB, hA, Wl3, bl3, Wr3, hB, flags, d_out);
    // layer 4: h=B -> mean in A (unweighted), out -> d_out
    gather_mean<false><<<2048, 256, 0, stream>>>(hB, csr_pk, row_st, deg, inv_deg, hA);
    transform_mfma<C_NUM, false, true><<<NBt, 256, 0, stream>>>(
        hA, hB, Wl4, bl4, Wr4, nullptr, flags, d_out);
}